// Round 17
// baseline (104.203 us; speedup 1.0000x reference)
//
#include <hip/hip_runtime.h>
#include <hip/hip_bf16.h>
#include <stdint.h>

#define NSEQ 1024
#define EMB 768
#define HEADS 12
#define HD 64
#define BATCH 8
#define BHN (BATCH*HEADS)

typedef __attribute__((ext_vector_type(8))) short bf16x8;
typedef __attribute__((ext_vector_type(4))) float f32x4;

typedef const void __attribute__((address_space(1))) cglobal_void;
typedef void __attribute__((address_space(3))) lds_void_t;

#define LOG2E 1.4426950408889634f

__device__ __forceinline__ void load_lds16(const void* g, void* l) {
    __builtin_amdgcn_global_load_lds((cglobal_void*)g, (lds_void_t*)l, 16, 0, 0);
}

__device__ __forceinline__ unsigned short f2bf(float f) {
    __hip_bfloat16 h = __float2bfloat16(f);
    return *reinterpret_cast<unsigned short*>(&h);
}

__device__ __forceinline__ unsigned int cvt_pk_bf16(float lo, float hi) {
    unsigned int r;
    asm("v_cvt_pk_bf16_f32 %0, %1, %2" : "=v"(r) : "v"(lo), "v"(hi));
    return r;
}

__device__ __forceinline__ float exp2_hw(float x) {
#if __has_builtin(__builtin_amdgcn_exp2f)
    return __builtin_amdgcn_exp2f(x);
#else
    return exp2f(x);
#endif
}

// ---------------- fused prep: conv_x + transpose w_qkv + transpose w_proj + bias ------
__global__ void prep_kernel(const float* __restrict__ x, unsigned short* __restrict__ xb,
                            const float* __restrict__ w_qkv, unsigned short* __restrict__ wt_qkv,
                            const float* __restrict__ w_proj, unsigned short* __restrict__ wt_proj,
                            const float* __restrict__ b_qkv, float* __restrict__ biasp) {
    __shared__ unsigned short tile[64][65];
    int bx = blockIdx.x, t = threadIdx.x;
    if (bx < 6144) {
        int i = (bx * 256 + t) * 4;
        float4 v = *reinterpret_cast<const float4*>(x + i);
        ushort4 o;
        o.x = f2bf(v.x); o.y = f2bf(v.y); o.z = f2bf(v.z); o.w = f2bf(v.w);
        *reinterpret_cast<ushort4*>(xb + i) = o;
        return;
    }
    if (bx < 6720) {
        bool perm = (bx < 6576);
        int bb = perm ? bx - 6144 : bx - 6576;
        int tilesC = perm ? 36 : 12;
        int C = perm ? 3 * EMB : EMB;
        const float* w = perm ? w_qkv : w_proj;
        unsigned short* wt = perm ? wt_qkv : wt_proj;
        int c0 = (bb % tilesC) * 64, k0 = (bb / tilesC) * 64;
        int r = t >> 2, cc = (t & 3) * 16;
#pragma unroll
        for (int e = 0; e < 16; e += 4) {
            float4 v = *reinterpret_cast<const float4*>(w + (size_t)(k0 + r) * C + c0 + cc + e);
            float s0 = (perm && ((c0 + cc + e + 0) % 3 == 0)) ? LOG2E : 1.0f;
            float s1 = (perm && ((c0 + cc + e + 1) % 3 == 0)) ? LOG2E : 1.0f;
            float s2 = (perm && ((c0 + cc + e + 2) % 3 == 0)) ? LOG2E : 1.0f;
            float s3 = (perm && ((c0 + cc + e + 3) % 3 == 0)) ? LOG2E : 1.0f;
            tile[r][cc + e + 0] = f2bf(v.x * s0);
            tile[r][cc + e + 1] = f2bf(v.y * s1);
            tile[r][cc + e + 2] = f2bf(v.z * s2);
            tile[r][cc + e + 3] = f2bf(v.w * s3);
        }
        __syncthreads();
        int c = t >> 2, kk0 = (t & 3) * 16;
        int cg = c0 + c;
        int n;
        if (perm) {
            int qkv = cg % 3, h = cg / 192, d = (cg % 192) / 3;
            n = qkv * EMB + h * HD + d;
        } else {
            n = cg;
        }
        uint4 lo, hi;
        lo.x = (unsigned)tile[kk0 + 0][c] | ((unsigned)tile[kk0 + 1][c] << 16);
        lo.y = (unsigned)tile[kk0 + 2][c] | ((unsigned)tile[kk0 + 3][c] << 16);
        lo.z = (unsigned)tile[kk0 + 4][c] | ((unsigned)tile[kk0 + 5][c] << 16);
        lo.w = (unsigned)tile[kk0 + 6][c] | ((unsigned)tile[kk0 + 7][c] << 16);
        hi.x = (unsigned)tile[kk0 + 8][c] | ((unsigned)tile[kk0 + 9][c] << 16);
        hi.y = (unsigned)tile[kk0 + 10][c] | ((unsigned)tile[kk0 + 11][c] << 16);
        hi.z = (unsigned)tile[kk0 + 12][c] | ((unsigned)tile[kk0 + 13][c] << 16);
        hi.w = (unsigned)tile[kk0 + 14][c] | ((unsigned)tile[kk0 + 15][c] << 16);
        *reinterpret_cast<uint4*>(wt + (size_t)n * EMB + k0 + kk0) = lo;
        *reinterpret_cast<uint4*>(wt + (size_t)n * EMB + k0 + kk0 + 8) = hi;
        return;
    }
    {
        int c = (bx - 6720) * 256 + t;
        if (c < 3 * EMB) {
            int qkv = c % 3, h = c / 192, d = (c % 192) / 3;
            biasp[qkv * EMB + h * HD + d] = (qkv == 0) ? b_qkv[c] * LOG2E : b_qkv[c];
        }
        return;
    }
}

// ---------------- fused QKV GEMM (TN=18), 128x128 tiles — R11/R13-proven ----------------
__launch_bounds__(256, 4)
__global__ void gemm_qkv_kernel(const unsigned short* __restrict__ A,
                                const unsigned short* __restrict__ Bt,
                                const float* __restrict__ bias,
                                unsigned short* __restrict__ qout,
                                unsigned short* __restrict__ kout,
                                unsigned short* __restrict__ vout) {
    constexpr int TN = 18;
    constexpr int NWG = 64 * TN;
    constexpr int CHUNK = NWG / 8;
    constexpr int K = EMB;
    __shared__ unsigned short lds_a[128 * 64];
    __shared__ unsigned short lds_b[128 * 64];
    int bx0 = blockIdx.x;
    int bx = (bx0 % 8) * CHUNK + bx0 / 8;
    int tm = bx / TN, tn = bx % TN;
    bool vpath = (tn >= 12);
    const unsigned short* Bt_eff = Bt + (vpath ? (size_t)1536 * K : (size_t)0);
    const float* bias_eff = bias + (vpath ? 1536 : 0);
    int n0 = (vpath ? tn - 12 : tn) * 128;
    int m0 = tm * 128;
    int t = threadIdx.x;
    int l = t & 63;
    int g = l >> 4, c16 = l & 15;
    int wr = (t >> 7) & 1, wc = (t >> 6) & 1;
    int wbase = (t & 192);

    const char* baseA_f = vpath ? (const char*)lds_b : (const char*)lds_a;
    const char* baseB_f = vpath ? (const char*)lds_a : (const char*)lds_b;
    int roA = (vpath ? wc : wr) * 64;
    int roB = (vpath ? wr : wc) * 64;

    f32x4 acc[4][4];
#pragma unroll
    for (int i = 0; i < 4; i++)
#pragma unroll
        for (int j = 0; j < 4; j++)
#pragma unroll
            for (int r = 0; r < 4; r++) acc[i][j][r] = 0.f;

    for (int kt = 0; kt < K; kt += 64) {
        __syncthreads();
#pragma unroll
        for (int i = 0; i < 4; i++) {
            int c = i * 256 + t;
            int row = c >> 3;
            int sc = ((c & 7) ^ (row & 7)) * 8;
            load_lds16(A + (size_t)(m0 + row) * K + kt + sc, lds_a + (size_t)(i * 256 + wbase) * 8);
            load_lds16(Bt_eff + (size_t)(n0 + row) * K + kt + sc, lds_b + (size_t)(i * 256 + wbase) * 8);
        }
        __syncthreads();
#pragma unroll
        for (int kk = 0; kk < 2; kk++) {
            int cb = kk * 64 + g * 16;
            bf16x8 fa[4], fb[4];
#pragma unroll
            for (int i = 0; i < 4; i++) {
                int row = roA + i * 16 + c16;
                fa[i] = *reinterpret_cast<const bf16x8*>(
                    baseA_f + row * 128 + (cb ^ ((row & 7) << 4)));
            }
#pragma unroll
            for (int j = 0; j < 4; j++) {
                int row = roB + j * 16 + c16;
                fb[j] = *reinterpret_cast<const bf16x8*>(
                    baseB_f + row * 128 + (cb ^ ((row & 7) << 4)));
            }
#pragma unroll
            for (int i = 0; i < 4; i++)
#pragma unroll
                for (int j = 0; j < 4; j++)
                    acc[i][j] = __builtin_amdgcn_mfma_f32_16x16x32_bf16(fa[i], fb[j], acc[i][j], 0, 0, 0);
        }
    }

    if (vpath) {
#pragma unroll
        for (int i = 0; i < 4; i++) {
#pragma unroll
            for (int r = 0; r < 4; r++) {
                int nv = wc * 64 + i * 16 + (g * 4) + r + n0;
                float bv = bias_eff[nv];
                int hh = nv >> 6, dd = nv & 63;
#pragma unroll
                for (int j = 0; j < 4; j++) {
                    int m_g = m0 + wr * 64 + j * 16 + c16;
                    int bb = m_g >> 10, nn = m_g & 1023;
                    int nnp = (nn & ~31) | ((nn & 12) << 1) | ((nn >> 2) & 4) | (nn & 3);
                    vout[((size_t)(bb * HEADS + hh) * HD + dd) * NSEQ + nnp] =
                        f2bf(acc[i][j][r] + bv);
                }
            }
        }
    } else {
#pragma unroll
        for (int i = 0; i < 4; i++) {
            int mbase = m0 + wr * 64 + i * 16 + (g * 4);
#pragma unroll
            for (int j = 0; j < 4; j++) {
                int n_g = n0 + wc * 64 + j * 16 + c16;
                float bv = bias_eff[n_g];
#pragma unroll
                for (int r = 0; r < 4; r++) {
                    int m_g = mbase + r;
                    float v = acc[i][j][r] + bv;
                    int rem = n_g - ((n_g >= 768) ? 768 : 0);
                    int hh = rem >> 6, dd = rem & 63;
                    int bb = m_g >> 10, nn = m_g & 1023;
                    if (n_g < 768)
                        qout[(size_t)((bb * HEADS + hh) * NSEQ + nn) * HD + dd] = f2bf(v);
                    else
                        kout[(size_t)((bb * HEADS + hh) * NSEQ + nn) * HD + dd] = f2bf(v);
                }
            }
        }
    }
}

// ---------------- proj GEMM: 64x128 tiles, 768 blocks — R11-proven ----------------
__launch_bounds__(256, 4)
__global__ void proj_kernel(const unsigned short* __restrict__ A,
                            const unsigned short* __restrict__ Bt,
                            const float* __restrict__ bias,
                            float* __restrict__ out) {
    constexpr int TN = 6;
    constexpr int NWG = 128 * TN;
    constexpr int CHUNK = NWG / 8;
    constexpr int K = EMB;
    __shared__ unsigned short lds_a[64 * 64];
    __shared__ unsigned short lds_b[128 * 64];
    int bx0 = blockIdx.x;
    int bx = (bx0 % 8) * CHUNK + bx0 / 8;
    int tm = bx / TN, tn = bx % TN;
    int m0 = tm * 64, n0 = tn * 128;
    int t = threadIdx.x;
    int l = t & 63;
    int g = l >> 4, c16 = l & 15;
    int w = t >> 6;
    int wbase = (t & 192);

    f32x4 acc[4][2];
#pragma unroll
    for (int i = 0; i < 4; i++)
#pragma unroll
        for (int j = 0; j < 2; j++)
#pragma unroll
            for (int r = 0; r < 4; r++) acc[i][j][r] = 0.f;

    for (int kt = 0; kt < K; kt += 64) {
        __syncthreads();
#pragma unroll
        for (int i = 0; i < 2; i++) {
            int c = i * 256 + t;
            int row = c >> 3;
            int sc = ((c & 7) ^ (row & 7)) * 8;
            load_lds16(A + (size_t)(m0 + row) * K + kt + sc, lds_a + (size_t)(i * 256 + wbase) * 8);
        }
#pragma unroll
        for (int i = 0; i < 4; i++) {
            int c = i * 256 + t;
            int row = c >> 3;
            int sc = ((c & 7) ^ (row & 7)) * 8;
            load_lds16(Bt + (size_t)(n0 + row) * K + kt + sc, lds_b + (size_t)(i * 256 + wbase) * 8);
        }
        __syncthreads();
#pragma unroll
        for (int kk = 0; kk < 2; kk++) {
            int cb = kk * 64 + g * 16;
            bf16x8 fa[4], fb[2];
#pragma unroll
            for (int i = 0; i < 4; i++) {
                int row = i * 16 + c16;
                fa[i] = *reinterpret_cast<const bf16x8*>(
                    (const char*)lds_a + row * 128 + (cb ^ ((row & 7) << 4)));
            }
#pragma unroll
            for (int j = 0; j < 2; j++) {
                int row = w * 32 + j * 16 + c16;
                fb[j] = *reinterpret_cast<const bf16x8*>(
                    (const char*)lds_b + row * 128 + (cb ^ ((row & 7) << 4)));
            }
#pragma unroll
            for (int i = 0; i < 4; i++)
#pragma unroll
                for (int j = 0; j < 2; j++)
                    acc[i][j] = __builtin_amdgcn_mfma_f32_16x16x32_bf16(fa[i], fb[j], acc[i][j], 0, 0, 0);
        }
    }

#pragma unroll
    for (int i = 0; i < 4; i++) {
        int mbase = m0 + i * 16 + g * 4;
#pragma unroll
        for (int j = 0; j < 2; j++) {
            int n_g = n0 + w * 32 + j * 16 + c16;
            float bv = bias[n_g];
#pragma unroll
            for (int r = 0; r < 4; r++)
                out[(size_t)(mbase + r) * EMB + n_g] = acc[i][j][r] + bv;
        }
    }
}

// ---------------- flash attention: 2 waves x 64 q-rows (4 groups/wave) ----------------
// Each K/V fragment read feeds FOUR MFMAs -> per-CU LDS-read issue halved vs 4-wave/2-group.
// Single-state (8 independent MFMA chains per cluster provide dep-breaking). K,V double-
// buffered (32KB LDS); grid 768 = 3 blocks/CU all-resident, zero tail.
__launch_bounds__(128, 2)
__global__ void attn_kernel(const unsigned short* __restrict__ Q,
                            const unsigned short* __restrict__ K,
                            const unsigned short* __restrict__ Vt,
                            unsigned short* __restrict__ Oout) {
    __shared__ unsigned short k_lds[2][64 * 64];
    __shared__ unsigned short vt_lds[2][64 * 64];
    int bx = blockIdx.x;
    int bh = bx % BHN;          // 96 % 8 == 0 -> all q-tiles of a head share an XCD
    int q0 = (bx / BHN) << 7;
    int b = bh / HEADS, h = bh % HEADS;
    int t = threadIdx.x, w = t >> 6, l = t & 63;
    int g = l >> 4, c16 = l & 15;
    const unsigned short* Qh = Q + (size_t)bh * NSEQ * HD;
    const unsigned short* Kh = K + (size_t)bh * NSEQ * HD;
    const unsigned short* Vth = Vt + (size_t)bh * NSEQ * HD;

    // 4 q-groups per wave: qr(gi) = q0 + w*64 + gi*16 + c16
    bf16x8 qf[4][2];
#pragma unroll
    for (int gi = 0; gi < 4; gi++) {
        int qr = q0 + w * 64 + gi * 16 + c16;
        qf[gi][0] = *reinterpret_cast<const bf16x8*>(Qh + (size_t)qr * HD + g * 8);
        qf[gi][1] = *reinterpret_cast<const bf16x8*>(Qh + (size_t)qr * HD + 32 + g * 8);
    }

    f32x4 lv[4];
#pragma unroll
    for (int gi = 0; gi < 4; gi++)
#pragma unroll
        for (int r = 0; r < 4; r++) lv[gi][r] = 0.f;
    f32x4 acc[4][4];  // [group][jd]
#pragma unroll
    for (int gi = 0; gi < 4; gi++)
#pragma unroll
        for (int jd = 0; jd < 4; jd++)
#pragma unroll
            for (int r = 0; r < 4; r++) acc[gi][jd][r] = 0.f;

    // 128 threads: 4 passes each for K and V (64x64 bf16 = 512 lane-loads of 16B)
    auto stage = [&](unsigned short* kdst, unsigned short* vdst, int kv) {
#pragma unroll
        for (int i = 0; i < 4; i++) {
            int tt = i * 128 + t;
            int row = tt >> 3;
            int sc = ((tt & 7) ^ (row & 7)) * 8;
            load_lds16(Kh + (size_t)(kv + row) * HD + sc, kdst + (size_t)(tt & ~63) * 8);
            load_lds16(Vth + (size_t)row * NSEQ + kv + sc, vdst + (size_t)(tt & ~63) * 8);
        }
    };

    unsigned short* kcur = k_lds[0];
    unsigned short* knxt = k_lds[1];
    unsigned short* vcur = vt_lds[0];
    unsigned short* vnxt = vt_lds[1];

    stage(kcur, vcur, 0);
    __syncthreads();

    union PU { unsigned int u[4]; bf16x8 v; };

#pragma unroll 1
    for (int it = 0; it < 16; ++it) {
        if (it < 15) stage(knxt, vnxt, (it + 1) << 6);

        // S^T = K @ Q^T for 4 groups; each kf feeds 4 MFMAs
        f32x4 st[4][4];  // [group][jk]
#pragma unroll
        for (int gi = 0; gi < 4; gi++)
#pragma unroll
            for (int jk = 0; jk < 4; jk++)
#pragma unroll
                for (int r = 0; r < 4; r++) st[gi][jk][r] = 0.f;
        __builtin_amdgcn_s_setprio(1);
#pragma unroll
        for (int kk = 0; kk < 2; kk++) {
            int cb = kk * 64 + g * 16;
#pragma unroll
            for (int jk = 0; jk < 4; jk++) {
                int row = jk * 16 + c16;
                bf16x8 kf = *reinterpret_cast<const bf16x8*>(
                    (const char*)kcur + row * 128 + (cb ^ ((row & 7) << 4)));
#pragma unroll
                for (int gi = 0; gi < 4; gi++)
                    st[gi][jk] = __builtin_amdgcn_mfma_f32_16x16x32_bf16(kf, qf[gi][kk], st[gi][jk], 0, 0, 0);
            }
        }
        __builtin_amdgcn_s_setprio(0);

        // fixed-base softmax (exp2 domain) + HW bf16 pack
#pragma unroll
        for (int gi = 0; gi < 4; gi++)
#pragma unroll
            for (int jk = 0; jk < 4; jk++)
#pragma unroll
                for (int r = 0; r < 4; r++) st[gi][jk][r] = exp2_hw(st[gi][jk][r]);

        bf16x8 pf[4][2];
#pragma unroll
        for (int gi = 0; gi < 4; gi++) {
            PU p0, p1;
#pragma unroll
            for (int p = 0; p < 2; p++) {
                p0.u[p]     = cvt_pk_bf16(st[gi][0][2 * p], st[gi][0][2 * p + 1]);
                p0.u[2 + p] = cvt_pk_bf16(st[gi][1][2 * p], st[gi][1][2 * p + 1]);
                p1.u[p]     = cvt_pk_bf16(st[gi][2][2 * p], st[gi][2][2 * p + 1]);
                p1.u[2 + p] = cvt_pk_bf16(st[gi][3][2 * p], st[gi][3][2 * p + 1]);
            }
            pf[gi][0] = p0.v;
            pf[gi][1] = p1.v;
            lv[gi] += (st[gi][0] + st[gi][1]) + (st[gi][2] + st[gi][3]);
        }

        // O^T += V^T @ P^T ; each vf feeds 4 MFMAs
        __builtin_amdgcn_s_setprio(1);
#pragma unroll
        for (int ks = 0; ks < 2; ks++) {
            int cb = ks * 64 + g * 16;
#pragma unroll
            for (int jd = 0; jd < 4; jd++) {
                int row = jd * 16 + c16;
                bf16x8 vf = *reinterpret_cast<const bf16x8*>(
                    (const char*)vcur + row * 128 + (cb ^ ((row & 7) << 4)));
#pragma unroll
                for (int gi = 0; gi < 4; gi++)
                    acc[gi][jd] = __builtin_amdgcn_mfma_f32_16x16x32_bf16(vf, pf[gi][ks], acc[gi][jd], 0, 0, 0);
            }
        }
        __builtin_amdgcn_s_setprio(0);

        __syncthreads();  // stage(next) complete + all reads of cur done
        unsigned short* tk = kcur; kcur = knxt; knxt = tk;
        unsigned short* tv = vcur; vcur = vnxt; vnxt = tv;
    }

    // epilogue: per-group denominator reduce, normalize, store
    const float scale = 27.712812921102035f;  // sqrt(768)
#pragma unroll
    for (int gi = 0; gi < 4; gi++) {
        float lsum = (lv[gi][0] + lv[gi][1]) + (lv[gi][2] + lv[gi][3]);
        lsum += __shfl_xor(lsum, 16);
        lsum += __shfl_xor(lsum, 32);
        float inv = 1.0f / (lsum * scale);
        int qr = q0 + w * 64 + gi * 16 + c16;
        size_t qbase = ((size_t)(b * NSEQ + qr) * HEADS + h) * HD;
#pragma unroll
        for (int jd = 0; jd < 4; jd++)
#pragma unroll
            for (int r = 0; r < 4; r++) {
                int d = jd * 16 + g * 4 + r;
                Oout[qbase + d] = f2bf(acc[gi][jd][r] * inv);
            }
    }
}

extern "C" void kernel_launch(void* const* d_in, const int* in_sizes, int n_in,
                              void* d_out, int out_size, void* d_ws, size_t ws_size,
                              hipStream_t stream) {
    const float* x = (const float*)d_in[0];
    const float* w_qkv = (const float*)d_in[1];
    const float* b_qkv = (const float*)d_in[2];
    const float* w_proj = (const float*)d_in[3];
    const float* b_proj = (const float*)d_in[4];

    char* ws = (char*)d_ws;
    unsigned short* xb      = (unsigned short*)(ws + 0);
    unsigned short* wt_qkv  = (unsigned short*)(ws + 12582912);
    unsigned short* wt_proj = (unsigned short*)(ws + 16121856);
    float*          biasp   = (float*)(ws + 17301504);
    unsigned short* qb      = (unsigned short*)(ws + 17310720);
    unsigned short* kb      = (unsigned short*)(ws + 29893632);
    unsigned short* vtb     = (unsigned short*)(ws + 42476544);
    unsigned short* ao      = (unsigned short*)(ws + 55059456);

    prep_kernel<<<6729, 256, 0, stream>>>(x, xb, w_qkv, wt_qkv, w_proj, wt_proj, b_qkv, biasp);
    gemm_qkv_kernel<<<64 * 18, 256, 0, stream>>>(xb, wt_qkv, biasp, qb, kb, vtb);
    // attention: 768 blocks x 128 threads (2 waves x 64 q-rows)
    attn_kernel<<<BHN * 8, 128, 0, stream>>>(qb, kb, vtb, ao);
    proj_kernel<<<128 * 6, 256, 0, stream>>>(ao, wt_proj, b_proj, (float*)d_out);
}

// Round 18
// 99.492 us; speedup vs baseline: 1.0474x; 1.0474x over previous
//
#include <hip/hip_runtime.h>
#include <hip/hip_bf16.h>
#include <stdint.h>

#define NSEQ 1024
#define EMB 768
#define HEADS 12
#define HD 64
#define BATCH 8
#define BHN (BATCH*HEADS)

typedef __attribute__((ext_vector_type(8))) short bf16x8;
typedef __attribute__((ext_vector_type(4))) float f32x4;

typedef const void __attribute__((address_space(1))) cglobal_void;
typedef void __attribute__((address_space(3))) lds_void_t;

#define LOG2E 1.4426950408889634f

__device__ __forceinline__ void load_lds16(const void* g, void* l) {
    __builtin_amdgcn_global_load_lds((cglobal_void*)g, (lds_void_t*)l, 16, 0, 0);
}

__device__ __forceinline__ unsigned short f2bf(float f) {
    __hip_bfloat16 h = __float2bfloat16(f);
    return *reinterpret_cast<unsigned short*>(&h);
}

__device__ __forceinline__ unsigned int cvt_pk_bf16(float lo, float hi) {
    unsigned int r;
    asm("v_cvt_pk_bf16_f32 %0, %1, %2" : "=v"(r) : "v"(lo), "v"(hi));
    return r;
}

__device__ __forceinline__ float exp2_hw(float x) {
#if __has_builtin(__builtin_amdgcn_exp2f)
    return __builtin_amdgcn_exp2f(x);
#else
    return exp2f(x);
#endif
}

// ---------------- fused prep: conv_x + transpose w_qkv + transpose w_proj + bias ------
__global__ void prep_kernel(const float* __restrict__ x, unsigned short* __restrict__ xb,
                            const float* __restrict__ w_qkv, unsigned short* __restrict__ wt_qkv,
                            const float* __restrict__ w_proj, unsigned short* __restrict__ wt_proj,
                            const float* __restrict__ b_qkv, float* __restrict__ biasp) {
    __shared__ unsigned short tile[64][65];
    int bx = blockIdx.x, t = threadIdx.x;
    if (bx < 6144) {
        int i = (bx * 256 + t) * 4;
        float4 v = *reinterpret_cast<const float4*>(x + i);
        ushort4 o;
        o.x = f2bf(v.x); o.y = f2bf(v.y); o.z = f2bf(v.z); o.w = f2bf(v.w);
        *reinterpret_cast<ushort4*>(xb + i) = o;
        return;
    }
    if (bx < 6720) {
        bool perm = (bx < 6576);
        int bb = perm ? bx - 6144 : bx - 6576;
        int tilesC = perm ? 36 : 12;
        int C = perm ? 3 * EMB : EMB;
        const float* w = perm ? w_qkv : w_proj;
        unsigned short* wt = perm ? wt_qkv : wt_proj;
        int c0 = (bb % tilesC) * 64, k0 = (bb / tilesC) * 64;
        int r = t >> 2, cc = (t & 3) * 16;
#pragma unroll
        for (int e = 0; e < 16; e += 4) {
            float4 v = *reinterpret_cast<const float4*>(w + (size_t)(k0 + r) * C + c0 + cc + e);
            float s0 = (perm && ((c0 + cc + e + 0) % 3 == 0)) ? LOG2E : 1.0f;
            float s1 = (perm && ((c0 + cc + e + 1) % 3 == 0)) ? LOG2E : 1.0f;
            float s2 = (perm && ((c0 + cc + e + 2) % 3 == 0)) ? LOG2E : 1.0f;
            float s3 = (perm && ((c0 + cc + e + 3) % 3 == 0)) ? LOG2E : 1.0f;
            tile[r][cc + e + 0] = f2bf(v.x * s0);
            tile[r][cc + e + 1] = f2bf(v.y * s1);
            tile[r][cc + e + 2] = f2bf(v.z * s2);
            tile[r][cc + e + 3] = f2bf(v.w * s3);
        }
        __syncthreads();
        int c = t >> 2, kk0 = (t & 3) * 16;
        int cg = c0 + c;
        int n;
        if (perm) {
            int qkv = cg % 3, h = cg / 192, d = (cg % 192) / 3;
            n = qkv * EMB + h * HD + d;
        } else {
            n = cg;
        }
        uint4 lo, hi;
        lo.x = (unsigned)tile[kk0 + 0][c] | ((unsigned)tile[kk0 + 1][c] << 16);
        lo.y = (unsigned)tile[kk0 + 2][c] | ((unsigned)tile[kk0 + 3][c] << 16);
        lo.z = (unsigned)tile[kk0 + 4][c] | ((unsigned)tile[kk0 + 5][c] << 16);
        lo.w = (unsigned)tile[kk0 + 6][c] | ((unsigned)tile[kk0 + 7][c] << 16);
        hi.x = (unsigned)tile[kk0 + 8][c] | ((unsigned)tile[kk0 + 9][c] << 16);
        hi.y = (unsigned)tile[kk0 + 10][c] | ((unsigned)tile[kk0 + 11][c] << 16);
        hi.z = (unsigned)tile[kk0 + 12][c] | ((unsigned)tile[kk0 + 13][c] << 16);
        hi.w = (unsigned)tile[kk0 + 14][c] | ((unsigned)tile[kk0 + 15][c] << 16);
        *reinterpret_cast<uint4*>(wt + (size_t)n * EMB + k0 + kk0) = lo;
        *reinterpret_cast<uint4*>(wt + (size_t)n * EMB + k0 + kk0 + 8) = hi;
        return;
    }
    {
        int c = (bx - 6720) * 256 + t;
        if (c < 3 * EMB) {
            int qkv = c % 3, h = c / 192, d = (c % 192) / 3;
            biasp[qkv * EMB + h * HD + d] = (qkv == 0) ? b_qkv[c] * LOG2E : b_qkv[c];
        }
        return;
    }
}

// ---------------- fused QKV GEMM (TN=18), 128x128 tiles — R11/R13-proven ----------------
__launch_bounds__(256, 4)
__global__ void gemm_qkv_kernel(const unsigned short* __restrict__ A,
                                const unsigned short* __restrict__ Bt,
                                const float* __restrict__ bias,
                                unsigned short* __restrict__ qout,
                                unsigned short* __restrict__ kout,
                                unsigned short* __restrict__ vout) {
    constexpr int TN = 18;
    constexpr int NWG = 64 * TN;
    constexpr int CHUNK = NWG / 8;
    constexpr int K = EMB;
    __shared__ unsigned short lds_a[128 * 64];
    __shared__ unsigned short lds_b[128 * 64];
    int bx0 = blockIdx.x;
    int bx = (bx0 % 8) * CHUNK + bx0 / 8;
    int tm = bx / TN, tn = bx % TN;
    bool vpath = (tn >= 12);
    const unsigned short* Bt_eff = Bt + (vpath ? (size_t)1536 * K : (size_t)0);
    const float* bias_eff = bias + (vpath ? 1536 : 0);
    int n0 = (vpath ? tn - 12 : tn) * 128;
    int m0 = tm * 128;
    int t = threadIdx.x;
    int l = t & 63;
    int g = l >> 4, c16 = l & 15;
    int wr = (t >> 7) & 1, wc = (t >> 6) & 1;
    int wbase = (t & 192);

    const char* baseA_f = vpath ? (const char*)lds_b : (const char*)lds_a;
    const char* baseB_f = vpath ? (const char*)lds_a : (const char*)lds_b;
    int roA = (vpath ? wc : wr) * 64;
    int roB = (vpath ? wr : wc) * 64;

    f32x4 acc[4][4];
#pragma unroll
    for (int i = 0; i < 4; i++)
#pragma unroll
        for (int j = 0; j < 4; j++)
#pragma unroll
            for (int r = 0; r < 4; r++) acc[i][j][r] = 0.f;

    for (int kt = 0; kt < K; kt += 64) {
        __syncthreads();
#pragma unroll
        for (int i = 0; i < 4; i++) {
            int c = i * 256 + t;
            int row = c >> 3;
            int sc = ((c & 7) ^ (row & 7)) * 8;
            load_lds16(A + (size_t)(m0 + row) * K + kt + sc, lds_a + (size_t)(i * 256 + wbase) * 8);
            load_lds16(Bt_eff + (size_t)(n0 + row) * K + kt + sc, lds_b + (size_t)(i * 256 + wbase) * 8);
        }
        __syncthreads();
#pragma unroll
        for (int kk = 0; kk < 2; kk++) {
            int cb = kk * 64 + g * 16;
            bf16x8 fa[4], fb[4];
#pragma unroll
            for (int i = 0; i < 4; i++) {
                int row = roA + i * 16 + c16;
                fa[i] = *reinterpret_cast<const bf16x8*>(
                    baseA_f + row * 128 + (cb ^ ((row & 7) << 4)));
            }
#pragma unroll
            for (int j = 0; j < 4; j++) {
                int row = roB + j * 16 + c16;
                fb[j] = *reinterpret_cast<const bf16x8*>(
                    baseB_f + row * 128 + (cb ^ ((row & 7) << 4)));
            }
#pragma unroll
            for (int i = 0; i < 4; i++)
#pragma unroll
                for (int j = 0; j < 4; j++)
                    acc[i][j] = __builtin_amdgcn_mfma_f32_16x16x32_bf16(fa[i], fb[j], acc[i][j], 0, 0, 0);
        }
    }

    if (vpath) {
#pragma unroll
        for (int i = 0; i < 4; i++) {
#pragma unroll
            for (int r = 0; r < 4; r++) {
                int nv = wc * 64 + i * 16 + (g * 4) + r + n0;
                float bv = bias_eff[nv];
                int hh = nv >> 6, dd = nv & 63;
#pragma unroll
                for (int j = 0; j < 4; j++) {
                    int m_g = m0 + wr * 64 + j * 16 + c16;
                    int bb = m_g >> 10, nn = m_g & 1023;
                    int nnp = (nn & ~31) | ((nn & 12) << 1) | ((nn >> 2) & 4) | (nn & 3);
                    vout[((size_t)(bb * HEADS + hh) * HD + dd) * NSEQ + nnp] =
                        f2bf(acc[i][j][r] + bv);
                }
            }
        }
    } else {
#pragma unroll
        for (int i = 0; i < 4; i++) {
            int mbase = m0 + wr * 64 + i * 16 + (g * 4);
#pragma unroll
            for (int j = 0; j < 4; j++) {
                int n_g = n0 + wc * 64 + j * 16 + c16;
                float bv = bias_eff[n_g];
#pragma unroll
                for (int r = 0; r < 4; r++) {
                    int m_g = mbase + r;
                    float v = acc[i][j][r] + bv;
                    int rem = n_g - ((n_g >= 768) ? 768 : 0);
                    int hh = rem >> 6, dd = rem & 63;
                    int bb = m_g >> 10, nn = m_g & 1023;
                    if (n_g < 768)
                        qout[(size_t)((bb * HEADS + hh) * NSEQ + nn) * HD + dd] = f2bf(v);
                    else
                        kout[(size_t)((bb * HEADS + hh) * NSEQ + nn) * HD + dd] = f2bf(v);
                }
            }
        }
    }
}

// ---------------- proj GEMM: 64x128 tiles, 768 blocks — R11-proven ----------------
__launch_bounds__(256, 4)
__global__ void proj_kernel(const unsigned short* __restrict__ A,
                            const unsigned short* __restrict__ Bt,
                            const float* __restrict__ bias,
                            float* __restrict__ out) {
    constexpr int TN = 6;
    constexpr int NWG = 128 * TN;
    constexpr int CHUNK = NWG / 8;
    constexpr int K = EMB;
    __shared__ unsigned short lds_a[64 * 64];
    __shared__ unsigned short lds_b[128 * 64];
    int bx0 = blockIdx.x;
    int bx = (bx0 % 8) * CHUNK + bx0 / 8;
    int tm = bx / TN, tn = bx % TN;
    int m0 = tm * 64, n0 = tn * 128;
    int t = threadIdx.x;
    int l = t & 63;
    int g = l >> 4, c16 = l & 15;
    int w = t >> 6;
    int wbase = (t & 192);

    f32x4 acc[4][2];
#pragma unroll
    for (int i = 0; i < 4; i++)
#pragma unroll
        for (int j = 0; j < 2; j++)
#pragma unroll
            for (int r = 0; r < 4; r++) acc[i][j][r] = 0.f;

    for (int kt = 0; kt < K; kt += 64) {
        __syncthreads();
#pragma unroll
        for (int i = 0; i < 2; i++) {
            int c = i * 256 + t;
            int row = c >> 3;
            int sc = ((c & 7) ^ (row & 7)) * 8;
            load_lds16(A + (size_t)(m0 + row) * K + kt + sc, lds_a + (size_t)(i * 256 + wbase) * 8);
        }
#pragma unroll
        for (int i = 0; i < 4; i++) {
            int c = i * 256 + t;
            int row = c >> 3;
            int sc = ((c & 7) ^ (row & 7)) * 8;
            load_lds16(Bt + (size_t)(n0 + row) * K + kt + sc, lds_b + (size_t)(i * 256 + wbase) * 8);
        }
        __syncthreads();
#pragma unroll
        for (int kk = 0; kk < 2; kk++) {
            int cb = kk * 64 + g * 16;
            bf16x8 fa[4], fb[2];
#pragma unroll
            for (int i = 0; i < 4; i++) {
                int row = i * 16 + c16;
                fa[i] = *reinterpret_cast<const bf16x8*>(
                    (const char*)lds_a + row * 128 + (cb ^ ((row & 7) << 4)));
            }
#pragma unroll
            for (int j = 0; j < 2; j++) {
                int row = w * 32 + j * 16 + c16;
                fb[j] = *reinterpret_cast<const bf16x8*>(
                    (const char*)lds_b + row * 128 + (cb ^ ((row & 7) << 4)));
            }
#pragma unroll
            for (int i = 0; i < 4; i++)
#pragma unroll
                for (int j = 0; j < 2; j++)
                    acc[i][j] = __builtin_amdgcn_mfma_f32_16x16x32_bf16(fa[i], fb[j], acc[i][j], 0, 0, 0);
        }
    }

#pragma unroll
    for (int i = 0; i < 4; i++) {
        int mbase = m0 + i * 16 + g * 4;
#pragma unroll
        for (int j = 0; j < 2; j++) {
            int n_g = n0 + w * 32 + j * 16 + c16;
            float bv = bias[n_g];
#pragma unroll
            for (int r = 0; r < 4; r++)
                out[(size_t)(mbase + r) * EMB + n_g] = acc[i][j][r] + bv;
        }
    }
}

// ---------------- flash attention: QK(t) -> softmax(t-1) -> PV(t-1) — R13-proven ------
__launch_bounds__(256, 3)
__global__ void attn_kernel(const unsigned short* __restrict__ Q,
                            const unsigned short* __restrict__ K,
                            const unsigned short* __restrict__ Vt,
                            unsigned short* __restrict__ Oout) {
    __shared__ unsigned short k_lds[2][64 * 64];
    __shared__ unsigned short vt_lds[3][64 * 64];
    int bx = blockIdx.x;
    int bh = bx % BHN;
    int q0 = (bx / BHN) << 7;
    int b = bh / HEADS, h = bh % HEADS;
    int t = threadIdx.x, w = t >> 6, l = t & 63;
    int g = l >> 4, c16 = l & 15;
    const unsigned short* Qh = Q + (size_t)bh * NSEQ * HD;
    const unsigned short* Kh = K + (size_t)bh * NSEQ * HD;
    const unsigned short* Vth = Vt + (size_t)bh * NSEQ * HD;

    int qrA = q0 + w * 32 + c16;
    int qrB = qrA + 16;
    bf16x8 qfA[2], qfB[2];
    qfA[0] = *reinterpret_cast<const bf16x8*>(Qh + (size_t)qrA * HD + g * 8);
    qfA[1] = *reinterpret_cast<const bf16x8*>(Qh + (size_t)qrA * HD + 32 + g * 8);
    qfB[0] = *reinterpret_cast<const bf16x8*>(Qh + (size_t)qrB * HD + g * 8);
    qfB[1] = *reinterpret_cast<const bf16x8*>(Qh + (size_t)qrB * HD + 32 + g * 8);

    f32x4 lAv, lBv;
#pragma unroll
    for (int r = 0; r < 4; r++) { lAv[r] = 0.f; lBv[r] = 0.f; }
    f32x4 accA[4], accB[4];
#pragma unroll
    for (int jd = 0; jd < 4; jd++)
#pragma unroll
        for (int r = 0; r < 4; r++) { accA[jd][r] = 0.f; accB[jd][r] = 0.f; }

    auto stage = [&](unsigned short* kdst, unsigned short* vdst, int kv) {
#pragma unroll
        for (int i = 0; i < 2; i++) {
            int tt = i * 256 + t;
            int row = tt >> 3;
            int sc = ((tt & 7) ^ (row & 7)) * 8;
            load_lds16(Kh + (size_t)(kv + row) * HD + sc, kdst + (size_t)(tt & ~63) * 8);
            load_lds16(Vth + (size_t)row * NSEQ + kv + sc, vdst + (size_t)(tt & ~63) * 8);
        }
    };

    union PU { unsigned int u[4]; bf16x8 v; };
    bf16x8 pfA[2], pfB[2];
    auto softmax_pack = [&](f32x4 (&stA)[4], f32x4 (&stB)[4]) {
#pragma unroll
        for (int jk = 0; jk < 4; jk++)
#pragma unroll
            for (int r = 0; r < 4; r++) {
                stA[jk][r] = exp2_hw(stA[jk][r]);
                stB[jk][r] = exp2_hw(stB[jk][r]);
            }
        PU puA0, puA1, puB0, puB1;
#pragma unroll
        for (int p = 0; p < 2; p++) {
            puA0.u[p]     = cvt_pk_bf16(stA[0][2 * p], stA[0][2 * p + 1]);
            puA0.u[2 + p] = cvt_pk_bf16(stA[1][2 * p], stA[1][2 * p + 1]);
            puA1.u[p]     = cvt_pk_bf16(stA[2][2 * p], stA[2][2 * p + 1]);
            puA1.u[2 + p] = cvt_pk_bf16(stA[3][2 * p], stA[3][2 * p + 1]);
            puB0.u[p]     = cvt_pk_bf16(stB[0][2 * p], stB[0][2 * p + 1]);
            puB0.u[2 + p] = cvt_pk_bf16(stB[1][2 * p], stB[1][2 * p + 1]);
            puB1.u[p]     = cvt_pk_bf16(stB[2][2 * p], stB[2][2 * p + 1]);
            puB1.u[2 + p] = cvt_pk_bf16(stB[3][2 * p], stB[3][2 * p + 1]);
        }
        pfA[0] = puA0.v; pfA[1] = puA1.v;
        pfB[0] = puB0.v; pfB[1] = puB1.v;
        lAv += (stA[0] + stA[1]) + (stA[2] + stA[3]);
        lBv += (stB[0] + stB[1]) + (stB[2] + stB[3]);
    };

    auto qk_cluster = [&](const char* kbase, f32x4 (&stA)[4], f32x4 (&stB)[4]) {
#pragma unroll
        for (int kk = 0; kk < 2; kk++) {
            int cb = kk * 64 + g * 16;
#pragma unroll
            for (int jk = 0; jk < 4; jk++) {
                int row = jk * 16 + c16;
                bf16x8 kf = *reinterpret_cast<const bf16x8*>(
                    kbase + row * 128 + (cb ^ ((row & 7) << 4)));
                stA[jk] = __builtin_amdgcn_mfma_f32_16x16x32_bf16(kf, qfA[kk], stA[jk], 0, 0, 0);
                stB[jk] = __builtin_amdgcn_mfma_f32_16x16x32_bf16(kf, qfB[kk], stB[jk], 0, 0, 0);
            }
        }
    };
    auto pv_cluster = [&](const char* vbase) {
#pragma unroll
        for (int ks = 0; ks < 2; ks++) {
            int cb = ks * 64 + g * 16;
#pragma unroll
            for (int jd = 0; jd < 4; jd++) {
                int row = jd * 16 + c16;
                bf16x8 vf = *reinterpret_cast<const bf16x8*>(
                    vbase + row * 128 + (cb ^ ((row & 7) << 4)));
                accA[jd] = __builtin_amdgcn_mfma_f32_16x16x32_bf16(vf, pfA[ks], accA[jd], 0, 0, 0);
                accB[jd] = __builtin_amdgcn_mfma_f32_16x16x32_bf16(vf, pfB[ks], accB[jd], 0, 0, 0);
            }
        }
    };

    f32x4 sA0[4], sB0[4], sA1[4], sB1[4];

    unsigned short* kcur = k_lds[0];
    unsigned short* knxt = k_lds[1];
    unsigned short* vprev = vt_lds[2];
    unsigned short* vcur  = vt_lds[0];
    unsigned short* vnxt  = vt_lds[1];

    auto rotate = [&]() {
        unsigned short* tmp = kcur; kcur = knxt; knxt = tmp;
        unsigned short* tv = vprev; vprev = vcur; vcur = vnxt; vnxt = tv;
    };

    stage(kcur, vcur, 0);
    __syncthreads();

    {
        stage(knxt, vnxt, 64);
#pragma unroll
        for (int jk = 0; jk < 4; jk++)
#pragma unroll
            for (int r = 0; r < 4; r++) { sA0[jk][r] = 0.f; sB0[jk][r] = 0.f; }
        __builtin_amdgcn_s_setprio(1);
        qk_cluster((const char*)kcur, sA0, sB0);
        __builtin_amdgcn_s_setprio(0);
        __syncthreads();
        rotate();
    }

#pragma unroll 1
    for (int tt = 1; tt < 15; tt += 2) {
        {
            stage(knxt, vnxt, (tt + 1) << 6);
#pragma unroll
            for (int jk = 0; jk < 4; jk++)
#pragma unroll
                for (int r = 0; r < 4; r++) { sA1[jk][r] = 0.f; sB1[jk][r] = 0.f; }
            __builtin_amdgcn_s_setprio(1);
            qk_cluster((const char*)kcur, sA1, sB1);
            __builtin_amdgcn_s_setprio(0);
            softmax_pack(sA0, sB0);
            __builtin_amdgcn_s_setprio(1);
            pv_cluster((const char*)vprev);
            __builtin_amdgcn_s_setprio(0);
            __syncthreads();
            rotate();
        }
        {
            stage(knxt, vnxt, (tt + 2) << 6);
#pragma unroll
            for (int jk = 0; jk < 4; jk++)
#pragma unroll
                for (int r = 0; r < 4; r++) { sA0[jk][r] = 0.f; sB0[jk][r] = 0.f; }
            __builtin_amdgcn_s_setprio(1);
            qk_cluster((const char*)kcur, sA0, sB0);
            __builtin_amdgcn_s_setprio(0);
            softmax_pack(sA1, sB1);
            __builtin_amdgcn_s_setprio(1);
            pv_cluster((const char*)vprev);
            __builtin_amdgcn_s_setprio(0);
            __syncthreads();
            rotate();
        }
    }

    {
#pragma unroll
        for (int jk = 0; jk < 4; jk++)
#pragma unroll
            for (int r = 0; r < 4; r++) { sA1[jk][r] = 0.f; sB1[jk][r] = 0.f; }
        __builtin_amdgcn_s_setprio(1);
        qk_cluster((const char*)kcur, sA1, sB1);
        __builtin_amdgcn_s_setprio(0);
        softmax_pack(sA0, sB0);
        __builtin_amdgcn_s_setprio(1);
        pv_cluster((const char*)vprev);
        __builtin_amdgcn_s_setprio(0);
        __syncthreads();
        rotate();
    }
    softmax_pack(sA1, sB1);
    __builtin_amdgcn_s_setprio(1);
    pv_cluster((const char*)vprev);
    __builtin_amdgcn_s_setprio(0);

    float lA = (lAv[0] + lAv[1]) + (lAv[2] + lAv[3]);
    float lB = (lBv[0] + lBv[1]) + (lBv[2] + lBv[3]);
    lA += __shfl_xor(lA, 16);
    lA += __shfl_xor(lA, 32);
    lB += __shfl_xor(lB, 16);
    lB += __shfl_xor(lB, 32);
    const float scale = 27.712812921102035f;  // sqrt(768)
    float invA = 1.0f / (lA * scale);
    float invB = 1.0f / (lB * scale);
    size_t qbaseA = ((size_t)(b * NSEQ + qrA) * HEADS + h) * HD;
    size_t qbaseB = ((size_t)(b * NSEQ + qrB) * HEADS + h) * HD;
#pragma unroll
    for (int jd = 0; jd < 4; jd++)
#pragma unroll
        for (int r = 0; r < 4; r++) {
            int d = jd * 16 + g * 4 + r;
            Oout[qbaseA + d] = f2bf(accA[jd][r] * invA);
            Oout[qbaseB + d] = f2bf(accB[jd][r] * invB);
        }
}

extern "C" void kernel_launch(void* const* d_in, const int* in_sizes, int n_in,
                              void* d_out, int out_size, void* d_ws, size_t ws_size,
                              hipStream_t stream) {
    const float* x = (const float*)d_in[0];
    const float* w_qkv = (const float*)d_in[1];
    const float* b_qkv = (const float*)d_in[2];
    const float* w_proj = (const float*)d_in[3];
    const float* b_proj = (const float*)d_in[4];

    char* ws = (char*)d_ws;
    unsigned short* xb      = (unsigned short*)(ws + 0);
    unsigned short* wt_qkv  = (unsigned short*)(ws + 12582912);
    unsigned short* wt_proj = (unsigned short*)(ws + 16121856);
    float*          biasp   = (float*)(ws + 17301504);
    unsigned short* qb      = (unsigned short*)(ws + 17310720);
    unsigned short* kb      = (unsigned short*)(ws + 29893632);
    unsigned short* vtb     = (unsigned short*)(ws + 42476544);
    unsigned short* ao      = (unsigned short*)(ws + 55059456);

    prep_kernel<<<6729, 256, 0, stream>>>(x, xb, w_qkv, wt_qkv, w_proj, wt_proj, b_qkv, biasp);
    gemm_qkv_kernel<<<64 * 18, 256, 0, stream>>>(xb, wt_qkv, biasp, qb, kb, vtb);
    attn_kernel<<<BHN * 8, 256, 0, stream>>>(qb, kb, vtb, ao);
    proj_kernel<<<128 * 6, 256, 0, stream>>>(ao, wt_proj, b_proj, (float*)d_out);
}